// Round 10
// baseline (209.553 us; speedup 1.0000x reference)
//
#include <hip/hip_runtime.h>

// Correlation (FlowNet-style), kernel=1, stride=1, md=pad=4.
// B=8, C=128, H=W=192 -> out [8, 81, 192, 192] fp32.
//
// Round-10: R8 structure with f16 dot2 math (R9 + compile fix: cvt_pkrtz
// returns __fp16-vec on gfx950; route through union).
//  - x2 staged in LDS as channel-pair-interleaved half2: slot (pp, row, col)
//    holds (x2[c0,col], x2[c1,col]) packed by v_cvt_pkrtz_f16_f32 at staging.
//    Same stride-76 4B-slot geometry as R8 -> same (near-free) bank pattern.
//  - inner loop: acc[dx][q] = v_dot2_f32_f16(a2[q], rv[dx+q], acc) ->
//    2 MACs/lane/instr; LDS bytes per channel halved.
//  - chunk = 4 channels (2 pairs), double-buffered (12.2 KB), one barrier
//    per chunk (32 total), stage loads issued 2 chunks ahead.
//  - x1 read from global (L1/L2-hot, 9x reuse), packed to half2 on the fly.
//  - 576 tiles (8b x 3xt x 24yt), tile 8y x 64x; 3 dy-groups/tile ->
//    1728 blocks of 192 thr; XCD-chunked swizzle (XCD k == batch k).

#define NT 192

typedef _Float16 h2 __attribute__((ext_vector_type(2)));
typedef __fp16  p2 __attribute__((ext_vector_type(2)));
union U2 { float f; h2 h; p2 p; };

static __device__ __forceinline__ float pkf(float a, float b) {
  U2 u; u.p = __builtin_amdgcn_cvt_pkrtz(a, b); return u.f;
}
static __device__ __forceinline__ h2 asH2(float x) {
  U2 u; u.f = x; return u.h;
}

__global__ __launch_bounds__(NT, 2)
void corr_kernel(const float* __restrict__ x1g, const float* __restrict__ x2g,
                 float* __restrict__ outg) {
  constexpr int Cc = 128, Hh = 192, Ww = 192, HW = Hh * Ww;
  constexpr int CB = 4;                  // channels per chunk (2 pairs)
  constexpr int NCK = Cc / CB;           // 32 chunks
  constexpr int XS = 76;                 // row stride in half2 slots (304 B)
  constexpr int ROWS = 10;
  constexpr int CHF = ROWS * XS;         // 760 slots per pair
  constexpr int BUF = 2 * CHF;           // 1520 slots per buffer
  constexpr int NSLOT = 2 * ROWS * 18;   // 360 float4 staging slots

  __shared__ __align__(16) float lds[2 * BUF];  // 12.2 KB (slot = 4 B)

  // XCD-chunked swizzle: 1728 = 8 XCDs x 216; XCD k == batch k exactly.
  const int bid = blockIdx.x;
  const int wid = (bid & 7) * 216 + (bid >> 3);
  const int tile = wid / 3;
  const int g    = wid - 3 * tile;
  const int yt = tile % 24;
  const int t2 = tile / 24;
  const int xt = t2 % 3;
  const int b  = t2 / 3;
  const int y0 = yt * 8, x0 = xt * 64;

  const int tid  = (int)threadIdx.x;
  const int w    = tid >> 6;    // 0..2
  const int lane = tid & 63;
  const int tx   = lane & 7;    // 8 px each -> 64 cols
  const int ty   = lane >> 3;   // 8 rows
  const int dy   = 3 * g + w;

  const int y  = y0 + ty;
  const int xb = x0 + 8 * tx;

  // ---- staging descriptors (2 slots per thread; slot = pair x row x 4cols)
  const float* x2b = x2g + (size_t)(b * Cc) * HW;
  int  goff[2], loff[2];
  bool hasS[2], okS[2];
#pragma unroll
  for (int s = 0; s < 2; ++s) {
    const int idx = tid + s * NT;
    hasS[s] = (idx < NSLOT);
    const int pp = idx / 180;            // pair within chunk (0..1)
    const int rem = idx - pp * 180;
    const int i = rem / 18;              // row 0..9
    const int f = rem - 18 * i;          // float4 col group 0..17
    const int grow = y0 + 3 * g - 4 + i;
    const int gcol = x0 - 4 + 4 * f;
    okS[s] = hasS[s] && grow >= 0 && grow < Hh && gcol >= 0 && gcol <= Ww - 4;
    const int rc = grow < 0 ? 0 : (grow >= Hh ? Hh - 1 : grow);
    const int cl = gcol < 0 ? 0 : (gcol > Ww - 4 ? Ww - 4 : gcol);
    goff[s] = ((2 * pp) * Hh + rc) * Ww + cl;  // channel 2pp of the chunk
    loff[s] = pp * CHF + i * XS + 4 * f;
  }

  const float4 z4 = make_float4(0.f, 0.f, 0.f, 0.f);
  float4 se[2], so[2];   // even / odd channel of each slot's pair
  int gbase = 0;

  auto ldstage = [&]() {
#pragma unroll
    for (int s = 0; s < 2; ++s) {
      se[s] = okS[s] ? *(const float4*)(x2b + gbase + goff[s]) : z4;
      so[s] = okS[s] ? *(const float4*)(x2b + gbase + goff[s] + HW) : z4;
    }
    gbase += CB * HW;
  };
  auto dswr = [&](int base) {
#pragma unroll
    for (int s = 0; s < 2; ++s) {
      if (hasS[s]) {
        float4 v;
        v.x = pkf(se[s].x, so[s].x);
        v.y = pkf(se[s].y, so[s].y);
        v.z = pkf(se[s].z, so[s].z);
        v.w = pkf(se[s].w, so[s].w);
        *(float4*)&lds[base + loff[s]] = v;
      }
    }
  };

  const float* p1 = x1g + ((size_t)(b * Cc) * Hh + y) * Ww + xb;

  float acc[9][8];
#pragma unroll
  for (int d = 0; d < 9; ++d)
#pragma unroll
    for (int q = 0; q < 8; ++q) acc[d][q] = 0.f;

  // prologue: chunk0 -> buf0; issue chunk1 loads
  ldstage();
  dswr(0);
  ldstage();

  const int ro = (w + ty) * XS + 8 * tx;  // window base (half2 slots)

#pragma unroll 1
  for (int k = 0; k < NCK; ++k) {
    __syncthreads();  // buf[k&1] (chunk k) visible; prior readers done
    if (k + 1 < NCK) dswr(((k + 1) & 1) * BUF);  // write chunk k+1
    if (k + 2 < NCK) ldstage();                  // issue chunk k+2 loads
    const int base = (k & 1) * BUF;

    // x1 for this chunk's 4 channels (hoisted; L1/L2-hot)
    float4 xa[4][2];
#pragma unroll
    for (int c4 = 0; c4 < 4; ++c4) {
      xa[c4][0] = *(const float4*)(p1 + c4 * HW);
      xa[c4][1] = *(const float4*)(p1 + c4 * HW + 4);
    }
    p1 += 4 * HW;

#pragma unroll
    for (int pp = 0; pp < 2; ++pp) {
      h2 a2[8];
#pragma unroll
      for (int q = 0; q < 4; ++q) {
        a2[q]     = asH2(pkf(((const float*)&xa[2 * pp][0])[q],
                             ((const float*)&xa[2 * pp + 1][0])[q]));
        a2[4 + q] = asH2(pkf(((const float*)&xa[2 * pp][1])[q],
                             ((const float*)&xa[2 * pp + 1][1])[q]));
      }
      const float* rr = &lds[base + pp * CHF + ro];
      const float4 b0 = *(const float4*)(rr);
      const float4 b1 = *(const float4*)(rr + 4);
      const float4 b2 = *(const float4*)(rr + 8);
      const float4 b3 = *(const float4*)(rr + 12);
      h2 rv[16];
      const float bf[16] = {b0.x, b0.y, b0.z, b0.w, b1.x, b1.y, b1.z, b1.w,
                            b2.x, b2.y, b2.z, b2.w, b3.x, b3.y, b3.z, b3.w};
#pragma unroll
      for (int j = 0; j < 16; ++j) rv[j] = asH2(bf[j]);
#pragma unroll
      for (int dx = 0; dx < 9; ++dx)
#pragma unroll
        for (int q = 0; q < 8; ++q)
          acc[dx][q] =
              __builtin_amdgcn_fdot2(a2[q], rv[dx + q], acc[dx][q], false);
    }
  }

  // epilogue: out[b][dy*9+dx][y][xb..xb+7]
  const float invc = 1.0f / 128.0f;
#pragma unroll
  for (int dx = 0; dx < 9; ++dx) {
    float4 o0, o1;
    o0.x = acc[dx][0] * invc; o0.y = acc[dx][1] * invc;
    o0.z = acc[dx][2] * invc; o0.w = acc[dx][3] * invc;
    o1.x = acc[dx][4] * invc; o1.y = acc[dx][5] * invc;
    o1.z = acc[dx][6] * invc; o1.w = acc[dx][7] * invc;
    const size_t oidx =
        (((size_t)b * 81 + (dy * 9 + dx)) * Hh + y) * Ww + xb;
    *(float4*)&outg[oidx] = o0;
    *(float4*)&outg[oidx + 4] = o1;
  }
}

extern "C" void kernel_launch(void* const* d_in, const int* in_sizes, int n_in,
                              void* d_out, int out_size, void* d_ws, size_t ws_size,
                              hipStream_t stream) {
  const float* x1 = (const float*)d_in[0];
  const float* x2 = (const float*)d_in[1];
  float* out = (float*)d_out;
  // grid: 576 tiles x 3 dy-groups = 1728 blocks (divisible by 8 XCDs)
  corr_kernel<<<dim3(1728), dim3(NT), 0, stream>>>(x1, x2, out);
}

// Round 11
// 157.271 us; speedup vs baseline: 1.3324x; 1.3324x over previous
//
#include <hip/hip_runtime.h>

// Correlation (FlowNet-style), kernel=1, stride=1, md=pad=4.
// B=8, C=128, H=W=192 -> out [8, 81, 192, 192] fp32.
//
// Round-11: MFMA band-GEMM.
//  - per (b, y): out[dx, x] = sum_c x1[x, c] * x2[c, x+dx-4] = banded GEMM.
//    16-px x-tile, K=128 in 4 chunks of 32, f16 mfma_f32_16x16x32_f16:
//    2 j-tile MFMAs cover the 9-wide dx band (28% band util, ~2 PF pipe).
//  - block = 512 thr = 8 waves = 8 y rows; tile (b, 8y, 16x); 2304 blocks
//    (8b x 24yt x 12xt), XCD-chunked swizzle.
//  - x2 LDS: [16 rows][32 jcols][32 c] f16, c-contiguous -> A/B frag reads
//    are LINEAR 1024-B wave reads (no bank conflicts). Cols 24-31 unstaged:
//    they feed only dx>8 accs, which are never stored. Reg-staged + packed
//    (cvt_pkrtz), double-buffered, loads issued 2 chunks ahead.
//  - x1: no inter-wave reuse -> direct scalar loads into A frags, all 4
//    chunks prefetched at start (16 VGPR).
//  - acc[9 dy][2 jt] f32x4 = 72 VGPR. K-loop fully unrolled.
//  - epilogue: band-valid acc -> LDS out-tile [81][8][16] (reuses staging
//    LDS) -> coalesced float4 global writes.

#define NT 512

typedef __fp16 f16x8 __attribute__((ext_vector_type(8)));
typedef __fp16 p2 __attribute__((ext_vector_type(2)));
typedef float f32x4 __attribute__((ext_vector_type(4)));

union PK { p2 p; unsigned u; };
union FragA { f16x8 v; p2 p[4]; };

static __device__ __forceinline__ unsigned pku(float a, float b) {
  PK z; z.p = __builtin_amdgcn_cvt_pkrtz(a, b); return z.u;
}

__global__ __launch_bounds__(NT, 4)
void corr_kernel(const float* __restrict__ x1g, const float* __restrict__ x2g,
                 float* __restrict__ outg) {
  constexpr int Cc = 128, Hh = 192, Ww = 192;
  constexpr int HW = Hh * Ww;

  __shared__ __align__(16) char smem[65536];  // 2 x 32KB B-dbuf; out-tile reuse
  unsigned* sm32 = (unsigned*)smem;

  // XCD-chunked swizzle: 2304 = 8 XCDs x 288; yt fastest for L2 row sharing.
  const int bid = blockIdx.x;
  const int wid = (bid & 7) * 288 + (bid >> 3);
  const int yt = wid % 24;
  const int t2 = wid / 24;
  const int xbk = t2 % 12;
  const int b = t2 / 12;
  const int y0 = yt * 8, x0 = xbk * 16;

  const int tid = (int)threadIdx.x;
  const int wy = tid >> 6;      // wave = y row
  const int lane = tid & 63;
  const int lr = lane & 15;     // A row p / B col n / C col n
  const int lq = lane >> 4;     // k-block

  // ---------- A fragments: x1[c][y0+wy][x0+lr], c = kc*32 + lq*8 + e ----------
  FragA af[4];
  {
    const float* pA = x1g + (((size_t)b * Cc) * Hh + (y0 + wy)) * Ww + x0 + lr;
#pragma unroll
    for (int kc = 0; kc < 4; ++kc)
#pragma unroll
      for (int r = 0; r < 4; ++r) {
        const int c0 = kc * 32 + lq * 8 + 2 * r;
        af[kc].p[r] = __builtin_amdgcn_cvt_pkrtz(pA[(size_t)c0 * HW],
                                                 pA[(size_t)(c0 + 1) * HW]);
      }
  }

  // ---------- B staging: 1536 slots = (rho 16, cpair 16, jf 6) ----------
  // s = (rho*16 + cpair)*6 + jf ; thread handles s = tid + k*512, k=0..2.
  const float* bsrc[3];
  int loff[3];
  bool bok[3];
#pragma unroll
  for (int k = 0; k < 3; ++k) {
    const int s = tid + k * NT;
    const int jf = s % 6;
    const int t = s / 6;
    const int cpair = t & 15;
    const int rho = t >> 4;
    const int grow = y0 - 4 + rho;          // global x2 row
    const int gcol = x0 - 4 + 4 * jf;       // global x2 col (float4 start)
    const bool ok = (grow >= 0) && (grow < Hh) && (gcol >= 0) && (gcol <= Ww - 4);
    bok[k] = ok;
    bsrc[k] = x2g + ((size_t)(b * Cc + 2 * cpair) * Hh + (ok ? grow : 0)) * Ww +
              (ok ? gcol : 0);
    loff[k] = rho * 512 + jf * 64 + cpair;  // uint index: [rho][j=4jf][cpair]
  }

  unsigned pk[3][4];

  auto bload = [&](int kc) {
#pragma unroll
    for (int k = 0; k < 3; ++k) {
      float4 v0 = make_float4(0.f, 0.f, 0.f, 0.f), v1 = v0;
      if (bok[k]) {
        const float* p = bsrc[k] + (size_t)(kc * 32) * HW;
        v0 = *(const float4*)p;        // channel 2*cpair, cols j..j+3
        v1 = *(const float4*)(p + HW); // channel 2*cpair+1
      }
      pk[k][0] = pku(v0.x, v1.x);
      pk[k][1] = pku(v0.y, v1.y);
      pk[k][2] = pku(v0.z, v1.z);
      pk[k][3] = pku(v0.w, v1.w);
    }
  };
  auto bwrite = [&](int buf) {
    unsigned* d = sm32 + buf * 8192;
#pragma unroll
    for (int k = 0; k < 3; ++k)
#pragma unroll
      for (int kk = 0; kk < 4; ++kk)
        d[loff[k] + kk * 16] = pk[k][kk];
  };

  f32x4 acc[9][2];
#pragma unroll
  for (int dy = 0; dy < 9; ++dy)
#pragma unroll
    for (int jt = 0; jt < 2; ++jt)
      acc[dy][jt] = (f32x4){0.f, 0.f, 0.f, 0.f};

  bload(0);
  bwrite(0);
  bload(1);

  const int rb = lr * 64 + lq * 16;  // byte offset of frag lane within a rho-row

#pragma unroll
  for (int kc = 0; kc < 4; ++kc) {
    __syncthreads();                       // buf[kc&1] (chunk kc) ready
    if (kc + 1 < 4) bwrite((kc + 1) & 1);  // publish chunk kc+1
    if (kc + 2 < 4) bload(kc + 2);         // issue chunk kc+2 loads
    const char* base = smem + (kc & 1) * 32768;
#pragma unroll
    for (int dy = 0; dy < 9; ++dy) {
      const char* rp = base + (wy + dy) * 2048 + rb;
#pragma unroll
      for (int jt = 0; jt < 2; ++jt) {
        const f16x8 bf = *(const f16x8*)(rp + jt * 1024);  // linear 1KB/wave
        acc[dy][jt] = __builtin_amdgcn_mfma_f32_16x16x32_f16(
            af[kc].v, bf, acc[dy][jt], 0, 0, 0);
      }
    }
  }

  // ---------- epilogue: band extract -> LDS out-tile -> coalesced write ----
  __syncthreads();           // all compute done; staging LDS reusable
  float* ot = (float*)smem;  // [81 d][8 y][16 x] f32 = 41472 B
  const float invc = 1.0f / 128.0f;
#pragma unroll
  for (int dy = 0; dy < 9; ++dy)
#pragma unroll
    for (int jt = 0; jt < 2; ++jt)
#pragma unroll
      for (int r = 0; r < 4; ++r) {
        const int p = 4 * lq + r;          // C row = x pixel
        const int dx = jt * 16 + lr - p;   // C col n = p + dx
        if (dx >= 0 && dx < 9)
          ot[((dy * 9 + dx) * 8 + wy) * 16 + p] = acc[dy][jt][r] * invc;
      }
  __syncthreads();

  for (int s = tid; s < 2592; s += NT) {   // 81 d x 8 y x 4 float4
    const int d = s >> 5;
    const int yy = (s >> 2) & 7;
    const int xf = s & 3;
    const float4 v = *(const float4*)&ot[d * 128 + yy * 16 + xf * 4];
    *(float4*)&outg[(((size_t)b * 81 + d) * Hh + (y0 + yy)) * Ww + x0 + xf * 4] = v;
  }
}

extern "C" void kernel_launch(void* const* d_in, const int* in_sizes, int n_in,
                              void* d_out, int out_size, void* d_ws, size_t ws_size,
                              hipStream_t stream) {
  const float* x1 = (const float*)d_in[0];
  const float* x2 = (const float*)d_in[1];
  float* out = (float*)d_out;
  // grid: 8 b x 24 y-strips x 12 x-tiles = 2304 blocks (divisible by 8 XCDs)
  corr_kernel<<<dim3(2304), dim3(NT), 0, stream>>>(x1, x2, out);
}